// Round 1
// baseline (813.573 us; speedup 1.0000x reference)
//
#include <hip/hip_runtime.h>
#include <hip/hip_bf16.h>
#include <stdint.h>
#include <stddef.h>

typedef __attribute__((ext_vector_type(4))) float f32x4;
typedef __attribute__((ext_vector_type(8))) short s16x8;
typedef __attribute__((ext_vector_type(4))) short s16x4;

#define AS1 __attribute__((address_space(1)))
#define AS3 __attribute__((address_space(3)))

static __device__ __forceinline__ void gload_lds16(const void* g, void* l) {
  __builtin_amdgcn_global_load_lds((const AS1 void*)g, (AS3 void*)l, 16, 0, 0);
}

static __device__ __forceinline__ short bf16_bits(float f) {
  __hip_bfloat16 h = __float2bfloat16(f);
  union { __hip_bfloat16 h; short s; } u; u.h = h; return u.s;
}

// ---------------------------------------------------------------------------
// gemm_bt: C[M,N] = A[M,Kd] * Bt[N,Kd]^T   (bf16 inputs, fp32 accumulate)
// EPI 0: bf16 row-major store; EPI 1: fp32 row-major store;
// EPI 2: bf16 store transposed per batch: Vt[b][n][s], b=m>>12, s=m&4095
// Block 256 thr (4 waves 2x2). Tile 128x128, BK=32, double-buffered LDS,
// global_load_lds width-16 with pre-swizzled global source (rule #21):
// LDS[row][pslot] holds logical k-slot (pslot ^ (row&3)); reads un-swizzle.
// ---------------------------------------------------------------------------
template<int EPI>
__global__ __launch_bounds__(256, 2) void gemm_bt(
    const __hip_bfloat16* __restrict__ A,
    const __hip_bfloat16* __restrict__ Bt,
    void* __restrict__ Cv,
    int M, int N, int Kd)
{
  __shared__ __hip_bfloat16 lds[2][2][128][32];
  const int tid  = threadIdx.x;
  const int lane = tid & 63;
  const int wid  = tid >> 6;
  const int wm   = wid >> 1;
  const int wn   = wid & 1;
  const long bm  = (long)blockIdx.y * 128;
  const long bn  = (long)blockIdx.x * 128;

  const int lrow  = lane >> 2;  // 0..15 row within 16-row staging issue
  const int pslot = lane & 3;   // physical 16B slot this lane fills

  f32x4 acc[4][4];
#pragma unroll
  for (int i = 0; i < 4; ++i)
#pragma unroll
    for (int j = 0; j < 4; ++j)
      acc[i][j] = (f32x4){0.f, 0.f, 0.f, 0.f};

  const int NK = Kd >> 5;

  // stage tile kt into buffer buf: each wave covers rows [wid*32, wid*32+32)
  // of both A and B tiles (2 issues of 16 rows each, 1KB per issue).
#define STAGE(buf, kt)                                                         \
  {                                                                            \
    _Pragma("unroll")                                                          \
    for (int half = 0; half < 2; ++half) {                                     \
      const int r  = wid * 32 + half * 16 + lrow;                              \
      const int kA = ((kt) << 5) + ((pslot ^ (r & 3)) << 3);                   \
      gload_lds16(A  + (size_t)(bm + r) * Kd + kA,                             \
                  &lds[buf][0][wid * 32 + half * 16][0]);                      \
      gload_lds16(Bt + (size_t)(bn + r) * Kd + kA,                             \
                  &lds[buf][1][wid * 32 + half * 16][0]);                      \
    }                                                                          \
  }

  STAGE(0, 0);
  __syncthreads();

  for (int kt = 0; kt < NK; ++kt) {
    const int buf = kt & 1;
    if (kt + 1 < NK) STAGE(buf ^ 1, kt + 1);

    const int frow  = lane & 15;
    const int fslot = lane >> 4;   // logical k-slot (8 bf16 each)
    s16x8 af[4], bfv[4];
#pragma unroll
    for (int mi = 0; mi < 4; ++mi) {
      const int r = wm * 64 + mi * 16 + frow;
      af[mi] = *(const s16x8*)&lds[buf][0][r][(fslot ^ (r & 3)) << 3];
    }
#pragma unroll
    for (int ni = 0; ni < 4; ++ni) {
      const int r = wn * 64 + ni * 16 + frow;
      bfv[ni] = *(const s16x8*)&lds[buf][1][r][(fslot ^ (r & 3)) << 3];
    }
#pragma unroll
    for (int mi = 0; mi < 4; ++mi)
#pragma unroll
      for (int ni = 0; ni < 4; ++ni)
        acc[mi][ni] = __builtin_amdgcn_mfma_f32_16x16x32_bf16(
            af[mi], bfv[ni], acc[mi][ni], 0, 0, 0);

    __syncthreads();
  }

  // epilogue: C/D frag mapping col=lane&15, row=(lane>>4)*4+j  [m89]
  const int col   = lane & 15;
  const int rquad = (lane >> 4) << 2;
#pragma unroll
  for (int mi = 0; mi < 4; ++mi) {
#pragma unroll
    for (int ni = 0; ni < 4; ++ni) {
      const long m0 = bm + wm * 64 + mi * 16 + rquad;
      const long n  = bn + wn * 64 + ni * 16 + col;
#pragma unroll
      for (int j = 0; j < 4; ++j) {
        const float v = acc[mi][ni][j];
        if (EPI == 0) {
          ((__hip_bfloat16*)Cv)[(size_t)(m0 + j) * N + n] = __float2bfloat16(v);
        } else if (EPI == 1) {
          ((float*)Cv)[(size_t)(m0 + j) * N + n] = v;
        } else {
          const long m = m0 + j;
          const long b = m >> 12;
          const long s = m & 4095;
          ((__hip_bfloat16*)Cv)[(((b << 10) + n) << 12) + s] = __float2bfloat16(v);
        }
      }
    }
  }
}

// ---------------------------------------------------------------------------
__global__ __launch_bounds__(256) void cvt_f32_bf16(
    const float* __restrict__ x, __hip_bfloat16* __restrict__ o, long n)
{
  const long i = ((long)blockIdx.x * 256 + threadIdx.x) * 8;
  if (i >= n) return;
  f32x4 a = *(const f32x4*)(x + i);
  f32x4 b = *(const f32x4*)(x + i + 4);
  s16x8 r;
  r[0] = bf16_bits(a.x); r[1] = bf16_bits(a.y);
  r[2] = bf16_bits(a.z); r[3] = bf16_bits(a.w);
  r[4] = bf16_bits(b.x); r[5] = bf16_bits(b.y);
  r[6] = bf16_bits(b.z); r[7] = bf16_bits(b.w);
  *(s16x8*)((short*)o + i) = r;
}

// Wt[n][k] = W[k][n], fp32 -> bf16, D=1024
__global__ __launch_bounds__(256) void transpose_w_bf16(
    const float* __restrict__ W, __hip_bfloat16* __restrict__ Wt)
{
  __shared__ float t[32][33];
  const int tx = threadIdx.x & 31;
  const int ty = (threadIdx.x >> 5) * 4;
  const int bx = blockIdx.x * 32;  // n
  const int by = blockIdx.y * 32;  // k
#pragma unroll
  for (int j = 0; j < 4; ++j)
    t[ty + j][tx] = W[(size_t)(by + ty + j) * 1024 + bx + tx];
  __syncthreads();
#pragma unroll
  for (int j = 0; j < 4; ++j)
    Wt[(size_t)(bx + ty + j) * 1024 + by + tx] = __float2bfloat16(t[tx][ty + j]);
}

// row softmax: P[row,:] = softmax(scale * Sc[row,:]), 4096 wide, bf16 out
__global__ __launch_bounds__(256) void softmax_row(
    const float* __restrict__ Sc, __hip_bfloat16* __restrict__ P, float scale)
{
  __shared__ float red[4];
  const int t = threadIdx.x;
  const long row = blockIdx.x;
  const float* sr = Sc + row * 4096;
  float v[16];
  float mx = -3.4e38f;
#pragma unroll
  for (int c = 0; c < 4; ++c) {
    f32x4 a = *(const f32x4*)(sr + c * 1024 + t * 4);
    v[c*4+0] = a.x; v[c*4+1] = a.y; v[c*4+2] = a.z; v[c*4+3] = a.w;
    mx = fmaxf(mx, fmaxf(fmaxf(a.x, a.y), fmaxf(a.z, a.w)));
  }
#pragma unroll
  for (int off = 32; off >= 1; off >>= 1) mx = fmaxf(mx, __shfl_xor(mx, off));
  if ((t & 63) == 0) red[t >> 6] = mx;
  __syncthreads();
  mx = fmaxf(fmaxf(red[0], red[1]), fmaxf(red[2], red[3]));
  __syncthreads();

  float sum = 0.f;
#pragma unroll
  for (int i = 0; i < 16; ++i) { v[i] = __expf((v[i] - mx) * scale); sum += v[i]; }
#pragma unroll
  for (int off = 32; off >= 1; off >>= 1) sum += __shfl_xor(sum, off);
  if ((t & 63) == 0) red[t >> 6] = sum;
  __syncthreads();
  sum = red[0] + red[1] + red[2] + red[3];
  const float inv = 1.f / sum;

  short* pr = (short*)P + row * 4096;
#pragma unroll
  for (int c = 0; c < 4; ++c) {
    s16x4 o;
#pragma unroll
    for (int j = 0; j < 4; ++j) o[j] = bf16_bits(v[c*4+j] * inv);
    *(s16x4*)(pr + c * 1024 + t * 4) = o;
  }
}

// ---------------------------------------------------------------------------
extern "C" void kernel_launch(void* const* d_in, const int* in_sizes, int n_in,
                              void* d_out, int out_size, void* d_ws, size_t ws_size,
                              hipStream_t stream) {
  (void)in_sizes; (void)n_in; (void)out_size; (void)ws_size;
  const float* x  = (const float*)d_in[0];
  const float* Wq = (const float*)d_in[1];
  const float* Wk = (const float*)d_in[2];
  const float* Wv = (const float*)d_in[3];
  float* out = (float*)d_out;

  char* ws = (char*)d_ws;
  // layout (bytes): xb 32M | qb 32M | kb 32M | vt 32M | wt 3x2M | sc 64M | P 32M
  __hip_bfloat16* xb  = (__hip_bfloat16*)(ws);
  __hip_bfloat16* qb  = (__hip_bfloat16*)(ws + 33554432L);
  __hip_bfloat16* kb  = (__hip_bfloat16*)(ws + 67108864L);
  __hip_bfloat16* vt  = (__hip_bfloat16*)(ws + 100663296L);
  __hip_bfloat16* wtq = (__hip_bfloat16*)(ws + 134217728L);
  __hip_bfloat16* wtk = (__hip_bfloat16*)(ws + 136314880L);
  __hip_bfloat16* wtv = (__hip_bfloat16*)(ws + 138412032L);
  float*          sc  = (float*)        (ws + 140509184L);
  __hip_bfloat16* P   = (__hip_bfloat16*)(ws + 207618048L);
  // total 241172480 bytes

  cvt_f32_bf16<<<8192, 256, 0, stream>>>(x, xb, 16777216L);
  transpose_w_bf16<<<dim3(32, 32), 256, 0, stream>>>(Wq, wtq);
  transpose_w_bf16<<<dim3(32, 32), 256, 0, stream>>>(Wk, wtk);
  transpose_w_bf16<<<dim3(32, 32), 256, 0, stream>>>(Wv, wtv);

  // projections: [16384,1024] x [1024,1024]
  gemm_bt<0><<<dim3(8, 128), 256, 0, stream>>>(xb, wtq, qb, 16384, 1024, 1024);
  gemm_bt<0><<<dim3(8, 128), 256, 0, stream>>>(xb, wtk, kb, 16384, 1024, 1024);
  gemm_bt<2><<<dim3(8, 128), 256, 0, stream>>>(xb, wtv, vt, 16384, 1024, 1024);

  for (int b = 0; b < 4; ++b) {
    const __hip_bfloat16* Qb = qb + (size_t)b * 4096 * 1024;
    const __hip_bfloat16* Kb = kb + (size_t)b * 4096 * 1024;
    const __hip_bfloat16* Vt = vt + (size_t)b * 1024 * 4096;
    // scores = Q K^T  (fp32 out)
    gemm_bt<1><<<dim3(32, 32), 256, 0, stream>>>((const __hip_bfloat16*)Qb,
                                                 (const __hip_bfloat16*)Kb,
                                                 sc, 4096, 4096, 1024);
    // P = softmax(scale * scores), normalized, bf16
    softmax_row<<<4096, 256, 0, stream>>>(sc, P, 0.03125f);
    // O = P V  via  P[M=4096,K=4096] x Vt[N=1024,K=4096]^T, fp32 out
    gemm_bt<1><<<dim3(8, 32), 256, 0, stream>>>(P, Vt,
                                                out + (size_t)b * 4096 * 1024,
                                                4096, 1024, 4096);
  }
}

// Round 3
// 675.911 us; speedup vs baseline: 1.2037x; 1.2037x over previous
//
#include <hip/hip_runtime.h>
#include <hip/hip_bf16.h>
#include <hip/hip_fp16.h>
#include <stdint.h>
#include <stddef.h>

typedef __attribute__((ext_vector_type(4))) float f32x4;
typedef __attribute__((ext_vector_type(8))) short s16x8;
typedef __attribute__((ext_vector_type(4))) short s16x4;

#define AS1 __attribute__((address_space(1)))
#define AS3 __attribute__((address_space(3)))

static __device__ __forceinline__ void gload_lds16(const void* g, void* l) {
  __builtin_amdgcn_global_load_lds((const AS1 void*)g, (AS3 void*)l, 16, 0, 0);
}

static __device__ __forceinline__ short bf16_bits(float f) {
  __hip_bfloat16 h = __float2bfloat16(f);
  union { __hip_bfloat16 h; short s; } u; u.h = h; return u.s;
}
static __device__ __forceinline__ short f16_bits(float f) {
  __half h = __float2half(f);
  union { __half h; short s; } u; u.h = h; return u.s;
}
static __device__ __forceinline__ float f16_to_f32(short b) {
  union { short s; __half h; } u; u.s = b; return __half2float(u.h);
}

// ---------------------------------------------------------------------------
// gemm_bt: C[M,N] = A[M,Kd] * Bt[N,Kd]^T   (bf16 inputs, fp32 accumulate)
// z-batched via blockIdx.z with element strides zsA/zsB/zsC.
// EPI 1: fp32 row-major store
// EPI 3: merged-projection routed store: n<1024 -> Q bf16 [m][n];
//        n<2048 -> K bf16 [m][n-1024]; else V-transposed bf16 vt[b][n-2048][s]
//        (Cv = qb base; kb = +16M elems; vt = +32M elems)
// EPI 4: fp16 row-major store (scores; softmax converts in-place to bf16 P)
//
// Tile 128x128, BK=32, 4 waves (2x2), double-buffered LDS.
// LDS swizzle (both-sides, rule #21): physical 16B slot p at row r holds
// logical k-slot (p - (r>>1))&3. Reader wanting logical l reads
// p=(l+(r>>1))&3 -> the 16 rows of a fragment window span all 8 bank
// groups with exactly 2 lanes each (2-way = free, m136).
// ---------------------------------------------------------------------------
template<int EPI>
__global__ __launch_bounds__(256, 2) void gemm_bt(
    const __hip_bfloat16* __restrict__ A,
    const __hip_bfloat16* __restrict__ Bt,
    void* __restrict__ Cv,
    int M, int N, int Kd,
    long zsA, long zsB, long zsC)
{
  __shared__ __hip_bfloat16 lds[2][2][128][32];
  A  += (long)blockIdx.z * zsA;
  Bt += (long)blockIdx.z * zsB;

  const int tid  = threadIdx.x;
  const int lane = tid & 63;
  const int wid  = tid >> 6;
  const int wm   = wid >> 1;
  const int wn   = wid & 1;
  const long bm  = (long)blockIdx.y * 128;
  const long bn  = (long)blockIdx.x * 128;

  const int lrow  = lane >> 2;  // 0..15 row within 16-row staging issue
  const int pslot = lane & 3;   // physical 16B slot this lane fills

  f32x4 acc[4][4];
#pragma unroll
  for (int i = 0; i < 4; ++i)
#pragma unroll
    for (int j = 0; j < 4; ++j)
      acc[i][j] = (f32x4){0.f, 0.f, 0.f, 0.f};

  const int NK = Kd >> 5;

  // stage tile kt into buffer buf: each wave covers rows [wid*32, wid*32+32)
  // of both A and B tiles. Global source pre-permuted so linear LDS dest +
  // swizzled read = identity (rule #21).
#define STAGE(buf, kt)                                                         \
  {                                                                            \
    _Pragma("unroll")                                                          \
    for (int half = 0; half < 2; ++half) {                                     \
      const int r  = wid * 32 + half * 16 + lrow;                              \
      const int ks = (pslot - ((r >> 1) & 3)) & 3;                             \
      const int kA = ((kt) << 5) + (ks << 3);                                  \
      gload_lds16(A  + (size_t)(bm + r) * Kd + kA,                             \
                  &lds[buf][0][wid * 32 + half * 16][0]);                      \
      gload_lds16(Bt + (size_t)(bn + r) * Kd + kA,                             \
                  &lds[buf][1][wid * 32 + half * 16][0]);                      \
    }                                                                          \
  }

  STAGE(0, 0);
  __syncthreads();

  for (int kt = 0; kt < NK; ++kt) {
    const int buf = kt & 1;
    if (kt + 1 < NK) STAGE(buf ^ 1, kt + 1);

    const int frow  = lane & 15;
    const int fslot = lane >> 4;   // logical k-slot (8 bf16 each)
    s16x8 af[4], bfv[4];
#pragma unroll
    for (int mi = 0; mi < 4; ++mi) {
      const int r = wm * 64 + mi * 16 + frow;
      af[mi] = *(const s16x8*)&lds[buf][0][r][((fslot + (r >> 1)) & 3) << 3];
    }
#pragma unroll
    for (int ni = 0; ni < 4; ++ni) {
      const int r = wn * 64 + ni * 16 + frow;
      bfv[ni] = *(const s16x8*)&lds[buf][1][r][((fslot + (r >> 1)) & 3) << 3];
    }
#pragma unroll
    for (int mi = 0; mi < 4; ++mi)
#pragma unroll
      for (int ni = 0; ni < 4; ++ni)
        acc[mi][ni] = __builtin_amdgcn_mfma_f32_16x16x32_bf16(
            af[mi], bfv[ni], acc[mi][ni], 0, 0, 0);

    __syncthreads();
  }

  // epilogue: C/D frag mapping col=lane&15, row=(lane>>4)*4+j  [m89]
  const int col   = lane & 15;
  const int rquad = (lane >> 4) << 2;
#pragma unroll
  for (int mi = 0; mi < 4; ++mi) {
#pragma unroll
    for (int ni = 0; ni < 4; ++ni) {
      const long m0 = bm + wm * 64 + mi * 16 + rquad;
      const long n  = bn + wn * 64 + ni * 16 + col;
#pragma unroll
      for (int j = 0; j < 4; ++j) {
        const float v = acc[mi][ni][j];
        if (EPI == 1) {
          float* C = (float*)Cv + (long)blockIdx.z * zsC;
          C[(size_t)(m0 + j) * N + n] = v;
        } else if (EPI == 4) {
          short* C = (short*)Cv + (long)blockIdx.z * zsC;
          C[(size_t)(m0 + j) * N + n] = f16_bits(v);
        } else {  // EPI == 3, merged projection
          const int route = (int)(bn >> 10);  // uniform per block
          __hip_bfloat16* base = (__hip_bfloat16*)Cv + (long)route * 16777216L;
          const long nl = n & 1023;
          const long m  = m0 + j;
          if (route < 2) {
            base[(size_t)m * 1024 + nl] = __float2bfloat16(v);
          } else {
            const long b = m >> 12;
            const long s = m & 4095;
            base[(((b << 10) + nl) << 12) + s] = __float2bfloat16(v);
          }
        }
      }
    }
  }
}

// ---------------------------------------------------------------------------
__global__ __launch_bounds__(256) void cvt_f32_bf16(
    const float* __restrict__ x, __hip_bfloat16* __restrict__ o, long n)
{
  const long i = ((long)blockIdx.x * 256 + threadIdx.x) * 8;
  if (i >= n) return;
  f32x4 a = *(const f32x4*)(x + i);
  f32x4 b = *(const f32x4*)(x + i + 4);
  s16x8 r;
  r[0] = bf16_bits(a.x); r[1] = bf16_bits(a.y);
  r[2] = bf16_bits(a.z); r[3] = bf16_bits(a.w);
  r[4] = bf16_bits(b.x); r[5] = bf16_bits(b.y);
  r[6] = bf16_bits(b.z); r[7] = bf16_bits(b.w);
  *(s16x8*)((short*)o + i) = r;
}

// Wt[n][k] = W[k][n], fp32 -> bf16, D=1024
__global__ __launch_bounds__(256) void transpose_w_bf16(
    const float* __restrict__ W, __hip_bfloat16* __restrict__ Wt)
{
  __shared__ float t[32][33];
  const int tx = threadIdx.x & 31;
  const int ty = (threadIdx.x >> 5) * 4;
  const int bx = blockIdx.x * 32;  // n
  const int by = blockIdx.y * 32;  // k
#pragma unroll
  for (int j = 0; j < 4; ++j)
    t[ty + j][tx] = W[(size_t)(by + ty + j) * 1024 + bx + tx];
  __syncthreads();
#pragma unroll
  for (int j = 0; j < 4; ++j)
    Wt[(size_t)(bx + ty + j) * 1024 + by + tx] = __float2bfloat16(t[tx][ty + j]);
}

// In-place row softmax over fp16 scores -> bf16 probs, row width 4096.
// Each thread reads exactly the 16 columns it later writes (no cross-thread
// hazard -> in-place safe). P[row,:] = softmax(scale * S[row,:]).
__global__ __launch_bounds__(256) void softmax_inplace(
    short* __restrict__ scP, float scale)
{
  __shared__ float red[4];
  const int t = threadIdx.x;
  short* pr = scP + (long)blockIdx.x * 4096;

  s16x8 h0 = *(const s16x8*)(pr + t * 8);
  s16x8 h1 = *(const s16x8*)(pr + 2048 + t * 8);
  float v[16];
  float mx = -3.4e38f;
#pragma unroll
  for (int j = 0; j < 8; ++j) { v[j]     = f16_to_f32(h0[j]); }
#pragma unroll
  for (int j = 0; j < 8; ++j) { v[8 + j] = f16_to_f32(h1[j]); }
#pragma unroll
  for (int i = 0; i < 16; ++i) mx = fmaxf(mx, v[i]);
#pragma unroll
  for (int off = 32; off >= 1; off >>= 1) mx = fmaxf(mx, __shfl_xor(mx, off));
  if ((t & 63) == 0) red[t >> 6] = mx;
  __syncthreads();
  mx = fmaxf(fmaxf(red[0], red[1]), fmaxf(red[2], red[3]));
  __syncthreads();

  float sum = 0.f;
#pragma unroll
  for (int i = 0; i < 16; ++i) { v[i] = __expf((v[i] - mx) * scale); sum += v[i]; }
#pragma unroll
  for (int off = 32; off >= 1; off >>= 1) sum += __shfl_xor(sum, off);
  if ((t & 63) == 0) red[t >> 6] = sum;
  __syncthreads();
  sum = red[0] + red[1] + red[2] + red[3];
  const float inv = 1.f / sum;

  s16x8 o0, o1;
#pragma unroll
  for (int j = 0; j < 8; ++j) { o0[j] = bf16_bits(v[j] * inv); }
#pragma unroll
  for (int j = 0; j < 8; ++j) { o1[j] = bf16_bits(v[8 + j] * inv); }
  *(s16x8*)(pr + t * 8) = o0;
  *(s16x8*)(pr + 2048 + t * 8) = o1;
}

// ---------------------------------------------------------------------------
extern "C" void kernel_launch(void* const* d_in, const int* in_sizes, int n_in,
                              void* d_out, int out_size, void* d_ws, size_t ws_size,
                              hipStream_t stream) {
  (void)in_sizes; (void)n_in; (void)out_size; (void)ws_size;
  const float* x  = (const float*)d_in[0];
  const float* Wq = (const float*)d_in[1];
  const float* Wk = (const float*)d_in[2];
  const float* Wv = (const float*)d_in[3];
  float* out = (float*)d_out;

  char* ws = (char*)d_ws;
  // layout (bytes): qb 32M | kb 32M | vt 32M | wt 6M | scP 128M  = 235.2MB
  // xb (bf16 x, 32M) ALIASES the scP region head: xb is dead after the
  // projection GEMM; scP is first written by the scores GEMM afterwards.
  __hip_bfloat16* qb  = (__hip_bfloat16*)(ws);                // kb=qb+16M el, vt=qb+32M el
  __hip_bfloat16* kb  = (__hip_bfloat16*)(ws + 33554432L);
  __hip_bfloat16* vt  = (__hip_bfloat16*)(ws + 67108864L);
  __hip_bfloat16* wt  = (__hip_bfloat16*)(ws + 100663296L);   // [3072][1024]
  short*          scP = (short*)         (ws + 106954752L);   // [4][4096][4096] fp16->bf16
  __hip_bfloat16* xb  = (__hip_bfloat16*)(ws + 106954752L);   // alias (see above)
  // total 235,172,480 bytes < 241.2MB known-good budget

  cvt_f32_bf16<<<8192, 256, 0, stream>>>(x, xb, 16777216L);
  transpose_w_bf16<<<dim3(32, 32), 256, 0, stream>>>(Wq, wt);
  transpose_w_bf16<<<dim3(32, 32), 256, 0, stream>>>(Wk, wt + 1048576L);
  transpose_w_bf16<<<dim3(32, 32), 256, 0, stream>>>(Wv, wt + 2097152L);

  // merged QKV projection: [16384,1024] x [1024,3072]^T, routed epilogue
  gemm_bt<3><<<dim3(24, 128, 1), 256, 0, stream>>>(
      xb, wt, qb, 16384, 3072, 1024, 0L, 0L, 0L);

  // scores = Q K^T (fp16 out), z-batched over 4 batches: 4096 blocks
  gemm_bt<4><<<dim3(32, 32, 4), 256, 0, stream>>>(
      qb, kb, scP, 4096, 4096, 1024,
      4194304L, 4194304L, 16777216L);

  // P = softmax(scale * scores) in place (fp16 -> bf16), 16384 rows
  softmax_inplace<<<16384, 256, 0, stream>>>(scP, 0.03125f);

  // O = P V via P[4096,4096] x Vt[1024,4096]^T, z-batched: 1024 blocks = 4/CU
  gemm_bt<1><<<dim3(8, 32, 4), 256, 0, stream>>>(
      (const __hip_bfloat16*)scP, vt, out, 4096, 1024, 4096,
      16777216L, 4194304L, 4194304L);
}

// Round 4
// 628.962 us; speedup vs baseline: 1.2935x; 1.0746x over previous
//
#include <hip/hip_runtime.h>
#include <hip/hip_bf16.h>
#include <hip/hip_fp16.h>
#include <stdint.h>
#include <stddef.h>

typedef __attribute__((ext_vector_type(4))) float f32x4;
typedef __attribute__((ext_vector_type(8))) short s16x8;
typedef __attribute__((ext_vector_type(4))) short s16x4;

#define AS1 __attribute__((address_space(1)))
#define AS3 __attribute__((address_space(3)))

static __device__ __forceinline__ void gload_lds16(const void* g, void* l) {
  __builtin_amdgcn_global_load_lds((const AS1 void*)g, (AS3 void*)l, 16, 0, 0);
}

static __device__ __forceinline__ short bf16_bits(float f) {
  __hip_bfloat16 h = __float2bfloat16(f);
  union { __hip_bfloat16 h; short s; } u; u.h = h; return u.s;
}
static __device__ __forceinline__ short f16_bits(float f) {
  __half h = __float2half(f);
  union { __half h; short s; } u; u.h = h; return u.s;
}
static __device__ __forceinline__ float f16_to_f32(short b) {
  union { short s; __half h; } u; u.s = b; return __half2float(u.h);
}

#define WAITVM8   asm volatile("s_waitcnt vmcnt(8)" ::: "memory")
#define WAITVM4   asm volatile("s_waitcnt vmcnt(4)" ::: "memory")
#define WAITVM0   asm volatile("s_waitcnt vmcnt(0)" ::: "memory")
#define WAITLGKM0 asm volatile("s_waitcnt lgkmcnt(0)" ::: "memory")
#define SCHEDB    __builtin_amdgcn_sched_barrier(0)
#define SBAR      __builtin_amdgcn_s_barrier()

// ---------------------------------------------------------------------------
// gemm256_bt: C[M,N] = A[M,Kd] * Bt[N,Kd]^T (bf16 in, fp32 accum)
// 256x256 tile, BK=32, 8 waves (2m x 4n), per-wave C = 128x64 (8x4 frags).
// TRIPLE-buffered K-tiles, counted vmcnt (never drains to 0 in main loop),
// raw s_barrier (avoids compiler's vmcnt(0) drain at __syncthreads).
// Ledger (per wave, 4 gload_lds units per K-tile stage):
//   iter i: STAGE(tile i+2) -> vmcnt(8) leaves tiles i+1,i+2 in flight,
//   proves tile i landed; barrier makes that true for ALL waves' slices.
//   RAW safe. End-of-iter lgkmcnt(0)+barrier: all reads of buf[i%3]
//   consumed before iter i+1 stages tile i+3 into that same buffer. WAR safe.
// LDS k-slot swizzle (proven 0-conflict in r3): physical 16B slot p at row r
// holds logical slot (p-(r>>1))&3; staged via pre-permuted global source,
// read via p=(l+(r>>1))&3 (both-sides, rule #21).
// EPI 1: fp32 row-major; EPI 3: routed QKV projection; EPI 4: fp16 row-major.
// ---------------------------------------------------------------------------
template<int EPI>
__global__ __launch_bounds__(512, 2) void gemm256_bt(
    const __hip_bfloat16* __restrict__ A,
    const __hip_bfloat16* __restrict__ Bt,
    void* __restrict__ Cv,
    int M, int N, int Kd,
    long zsA, long zsB, long zsC)
{
  __shared__ __hip_bfloat16 lds[3][2][256][32];   // 96 KiB
  A  += (long)blockIdx.z * zsA;
  Bt += (long)blockIdx.z * zsB;

  const int tid  = threadIdx.x;
  const int lane = tid & 63;
  const int wid  = tid >> 6;    // 0..7
  const int wm   = wid >> 2;    // 0..1
  const int wn   = wid & 3;     // 0..3
  const long bm  = (long)blockIdx.y * 256;
  const long bn  = (long)blockIdx.x * 256;

  const int lrow  = lane >> 2;  // 0..15
  const int pslot = lane & 3;   // physical 16B slot this lane fills

  f32x4 acc[8][4];
#pragma unroll
  for (int i = 0; i < 8; ++i)
#pragma unroll
    for (int j = 0; j < 4; ++j)
      acc[i][j] = (f32x4){0.f, 0.f, 0.f, 0.f};

  const int NK = Kd >> 5;

  // Stage K-tile kt into buffer b. 8 waves x 2 halves cover 256 rows of A
  // and of B; per wave 4 gload_lds instructions (= 4 vmcnt units).
#define STAGE256(b, kt)                                                        \
  {                                                                            \
    _Pragma("unroll")                                                          \
    for (int half = 0; half < 2; ++half) {                                     \
      const int r  = wid * 32 + half * 16 + lrow;                              \
      const int ks = (pslot - ((r >> 1) & 3)) & 3;                             \
      const int kA = ((kt) << 5) + (ks << 3);                                  \
      gload_lds16(A  + (size_t)(bm + r) * Kd + kA,                             \
                  &lds[b][0][wid * 32 + half * 16][0]);                        \
      gload_lds16(Bt + (size_t)(bn + r) * Kd + kA,                             \
                  &lds[b][1][wid * 32 + half * 16][0]);                        \
    }                                                                          \
  }

  STAGE256(0, 0);
  if (NK > 1) STAGE256(1, 1);

  int buf = 0;   // buffer holding tile i
  int sb  = 2;   // buffer receiving tile i+2

  const int frow  = lane & 15;
  const int fslot = lane >> 4;  // logical k-slot

  for (int i = 0; i < NK; ++i) {
    if (i + 2 < NK) {
      STAGE256(sb, i + 2);
      WAITVM8;
    } else if (i + 2 == NK) {
      WAITVM4;
    } else {
      WAITVM0;
    }
    SCHEDB;
    SBAR;        // all waves' slices of tile i are in LDS
    SCHEDB;

    // B fragments first (shared across all mi), then per-mi A frag + 4 MFMA.
    s16x8 bfv[4];
#pragma unroll
    for (int ni = 0; ni < 4; ++ni) {
      const int r = wn * 64 + ni * 16 + frow;
      bfv[ni] = *(const s16x8*)&lds[buf][1][r][((fslot + (r >> 1)) & 3) << 3];
    }
    __builtin_amdgcn_s_setprio(1);
#pragma unroll
    for (int mi = 0; mi < 8; ++mi) {
      const int r = wm * 128 + mi * 16 + frow;
      const s16x8 af =
          *(const s16x8*)&lds[buf][0][r][((fslot + (r >> 1)) & 3) << 3];
#pragma unroll
      for (int ni = 0; ni < 4; ++ni)
        acc[mi][ni] = __builtin_amdgcn_mfma_f32_16x16x32_bf16(
            af, bfv[ni], acc[mi][ni], 0, 0, 0);
    }
    __builtin_amdgcn_s_setprio(0);

    WAITLGKM0;   // all this wave's ds_reads consumed
    SCHEDB;
    SBAR;        // nobody overwrites buf until every wave is done reading
    SCHEDB;

    buf = (buf == 2) ? 0 : buf + 1;
    sb  = (sb  == 2) ? 0 : sb  + 1;
  }

  // epilogue: C/D frag mapping col=lane&15, row=(lane>>4)*4+j  [m89]
  const int col   = lane & 15;
  const int rquad = (lane >> 4) << 2;
#pragma unroll
  for (int mi = 0; mi < 8; ++mi) {
#pragma unroll
    for (int ni = 0; ni < 4; ++ni) {
      const long m0 = bm + wm * 128 + mi * 16 + rquad;
      const long n  = bn + wn * 64 + ni * 16 + col;
#pragma unroll
      for (int j = 0; j < 4; ++j) {
        const float v = acc[mi][ni][j];
        if (EPI == 1) {
          float* C = (float*)Cv + (long)blockIdx.z * zsC;
          C[(size_t)(m0 + j) * N + n] = v;
        } else if (EPI == 4) {
          short* C = (short*)Cv + (long)blockIdx.z * zsC;
          C[(size_t)(m0 + j) * N + n] = f16_bits(v);
        } else {  // EPI == 3, merged projection (route uniform per block)
          const int route = (int)(bn >> 10);
          __hip_bfloat16* base = (__hip_bfloat16*)Cv + (long)route * 16777216L;
          const long nl = n & 1023;
          const long m  = m0 + j;
          if (route < 2) {
            base[(size_t)m * 1024 + nl] = __float2bfloat16(v);
          } else {
            const long b = m >> 12;
            const long s = m & 4095;
            base[(((b << 10) + nl) << 12) + s] = __float2bfloat16(v);
          }
        }
      }
    }
  }
}

// ---------------------------------------------------------------------------
__global__ __launch_bounds__(256) void cvt_f32_bf16(
    const float* __restrict__ x, __hip_bfloat16* __restrict__ o, long n)
{
  const long i = ((long)blockIdx.x * 256 + threadIdx.x) * 8;
  if (i >= n) return;
  f32x4 a = *(const f32x4*)(x + i);
  f32x4 b = *(const f32x4*)(x + i + 4);
  s16x8 r;
  r[0] = bf16_bits(a.x); r[1] = bf16_bits(a.y);
  r[2] = bf16_bits(a.z); r[3] = bf16_bits(a.w);
  r[4] = bf16_bits(b.x); r[5] = bf16_bits(b.y);
  r[6] = bf16_bits(b.z); r[7] = bf16_bits(b.w);
  *(s16x8*)((short*)o + i) = r;
}

// Wt[n][k] = W[k][n], fp32 -> bf16, D=1024
__global__ __launch_bounds__(256) void transpose_w_bf16(
    const float* __restrict__ W, __hip_bfloat16* __restrict__ Wt)
{
  __shared__ float t[32][33];
  const int tx = threadIdx.x & 31;
  const int ty = (threadIdx.x >> 5) * 4;
  const int bx = blockIdx.x * 32;  // n
  const int by = blockIdx.y * 32;  // k
#pragma unroll
  for (int j = 0; j < 4; ++j)
    t[ty + j][tx] = W[(size_t)(by + ty + j) * 1024 + bx + tx];
  __syncthreads();
#pragma unroll
  for (int j = 0; j < 4; ++j)
    Wt[(size_t)(bx + ty + j) * 1024 + by + tx] = __float2bfloat16(t[tx][ty + j]);
}

// In-place row softmax over fp16 scores -> bf16 probs, row width 4096.
__global__ __launch_bounds__(256) void softmax_inplace(
    short* __restrict__ scP, float scale)
{
  __shared__ float red[4];
  const int t = threadIdx.x;
  short* pr = scP + (long)blockIdx.x * 4096;

  s16x8 h0 = *(const s16x8*)(pr + t * 8);
  s16x8 h1 = *(const s16x8*)(pr + 2048 + t * 8);
  float v[16];
  float mx = -3.4e38f;
#pragma unroll
  for (int j = 0; j < 8; ++j) { v[j]     = f16_to_f32(h0[j]); }
#pragma unroll
  for (int j = 0; j < 8; ++j) { v[8 + j] = f16_to_f32(h1[j]); }
#pragma unroll
  for (int i = 0; i < 16; ++i) mx = fmaxf(mx, v[i]);
#pragma unroll
  for (int off = 32; off >= 1; off >>= 1) mx = fmaxf(mx, __shfl_xor(mx, off));
  if ((t & 63) == 0) red[t >> 6] = mx;
  __syncthreads();
  mx = fmaxf(fmaxf(red[0], red[1]), fmaxf(red[2], red[3]));
  __syncthreads();

  float sum = 0.f;
#pragma unroll
  for (int i = 0; i < 16; ++i) { v[i] = __expf((v[i] - mx) * scale); sum += v[i]; }
#pragma unroll
  for (int off = 32; off >= 1; off >>= 1) sum += __shfl_xor(sum, off);
  if ((t & 63) == 0) red[t >> 6] = sum;
  __syncthreads();
  sum = red[0] + red[1] + red[2] + red[3];
  const float inv = 1.f / sum;

  s16x8 o0, o1;
#pragma unroll
  for (int j = 0; j < 8; ++j) { o0[j] = bf16_bits(v[j] * inv); }
#pragma unroll
  for (int j = 0; j < 8; ++j) { o1[j] = bf16_bits(v[8 + j] * inv); }
  *(s16x8*)(pr + t * 8) = o0;
  *(s16x8*)(pr + 2048 + t * 8) = o1;
}

// ---------------------------------------------------------------------------
extern "C" void kernel_launch(void* const* d_in, const int* in_sizes, int n_in,
                              void* d_out, int out_size, void* d_ws, size_t ws_size,
                              hipStream_t stream) {
  (void)in_sizes; (void)n_in; (void)out_size; (void)ws_size;
  const float* x  = (const float*)d_in[0];
  const float* Wq = (const float*)d_in[1];
  const float* Wk = (const float*)d_in[2];
  const float* Wv = (const float*)d_in[3];
  float* out = (float*)d_out;

  char* ws = (char*)d_ws;
  // layout (bytes): qb 32M | kb 32M | vt 32M | wt 6M | scP 128M  = 235.2MB
  // xb (bf16 x, 32M) ALIASES scP head: dead after the projection GEMM.
  __hip_bfloat16* qb  = (__hip_bfloat16*)(ws);
  __hip_bfloat16* kb  = (__hip_bfloat16*)(ws + 33554432L);
  __hip_bfloat16* vt  = (__hip_bfloat16*)(ws + 67108864L);
  __hip_bfloat16* wt  = (__hip_bfloat16*)(ws + 100663296L);   // [3072][1024]
  short*          scP = (short*)         (ws + 106954752L);   // [4][4096][4096]
  __hip_bfloat16* xb  = (__hip_bfloat16*)(ws + 106954752L);   // alias

  cvt_f32_bf16<<<8192, 256, 0, stream>>>(x, xb, 16777216L);
  transpose_w_bf16<<<dim3(32, 32), 256, 0, stream>>>(Wq, wt);
  transpose_w_bf16<<<dim3(32, 32), 256, 0, stream>>>(Wk, wt + 1048576L);
  transpose_w_bf16<<<dim3(32, 32), 256, 0, stream>>>(Wv, wt + 2097152L);

  // merged QKV projection: [16384,1024] x [1024,3072]^T, routed epilogue
  gemm256_bt<3><<<dim3(12, 64, 1), 512, 0, stream>>>(
      xb, wt, qb, 16384, 3072, 1024, 0L, 0L, 0L);

  // scores = Q K^T (fp16 out), z-batched: 1024 blocks
  gemm256_bt<4><<<dim3(16, 16, 4), 512, 0, stream>>>(
      qb, kb, scP, 4096, 4096, 1024,
      4194304L, 4194304L, 16777216L);

  // P = softmax(scale * scores) in place (fp16 -> bf16)
  softmax_inplace<<<16384, 256, 0, stream>>>(scP, 0.03125f);

  // O = P V via P[4096,4096] x Vt[1024,4096]^T, z-batched: 256 blocks
  gemm256_bt<1><<<dim3(4, 16, 4), 512, 0, stream>>>(
      (const __hip_bfloat16*)scP, vt, out, 4096, 1024, 4096,
      16777216L, 4194304L, 4194304L);
}

// Round 5
// 593.046 us; speedup vs baseline: 1.3719x; 1.0606x over previous
//
#include <hip/hip_runtime.h>
#include <hip/hip_bf16.h>
#include <hip/hip_fp16.h>
#include <stdint.h>
#include <stddef.h>

typedef __attribute__((ext_vector_type(4))) float f32x4;
typedef __attribute__((ext_vector_type(8))) short s16x8;
typedef __attribute__((ext_vector_type(4))) short s16x4;

#define AS1 __attribute__((address_space(1)))
#define AS3 __attribute__((address_space(3)))

static __device__ __forceinline__ void gload_lds16(const void* g, void* l) {
  __builtin_amdgcn_global_load_lds((const AS1 void*)g, (AS3 void*)l, 16, 0, 0);
}

static __device__ __forceinline__ short bf16_bits(float f) {
  __hip_bfloat16 h = __float2bfloat16(f);
  union { __hip_bfloat16 h; short s; } u; u.h = h; return u.s;
}
static __device__ __forceinline__ short f16_bits(float f) {
  __half h = __float2half(f);
  union { __half h; short s; } u; u.h = h; return u.s;
}
static __device__ __forceinline__ float f16_to_f32(short b) {
  union { short s; __half h; } u; u.s = b; return __half2float(u.h);
}

#define WAITVM8   asm volatile("s_waitcnt vmcnt(8)" ::: "memory")
#define WAITVM4   asm volatile("s_waitcnt vmcnt(4)" ::: "memory")
#define WAITVM0   asm volatile("s_waitcnt vmcnt(0)" ::: "memory")
#define WAITLGKM0 asm volatile("s_waitcnt lgkmcnt(0)" ::: "memory")
#define SCHEDB    __builtin_amdgcn_sched_barrier(0)
#define SBAR      __builtin_amdgcn_s_barrier()

// ---------------------------------------------------------------------------
// gemm256_bt: C[M,N] = A[M,Kd] * Bt[N,Kd]^T (bf16 in, fp32 accum)
// 256x256 tile, BK=32, 8 waves (2m x 4n), per-wave C = 128x64 (8x4 frags).
// Triple-buffered K-tiles, counted vmcnt (never 0 in main loop), raw
// s_barrier. Ledger identical to round-4 (proven pass):
//   RAW: at iter i, outstanding <= {i:4, i+1:4, i+2:4}; vmcnt(8) proves
//        tile i landed; barrier extends to all waves.
//   WAR: staging targets the buffer freed by iter i-1's lgkmcnt(0)+barrier.
// NEW vs r4:
//   * mid-tile alignment barrier (pure s_barrier, no waits): splits the
//     32-MFMA cluster into two 16-MFMA phases so waves interleave LDS-port
//     and MFMA-pipe use instead of all reading at once.
//   * SWZ: XCD-compact work remap (assumes XCD = linear_bid % 8, the m157
//     heuristic; correctness-neutral). SWZ=1 scores: per z, XCD owns a
//     4bm x 8bn region (Q 2MB + K 4MB ~ L2). SWZ=2 PV: XCD owns 2 (z,bn)
//     pairs x all 16 bm (16 blocks share each streamed vt panel in L2).
// LDS k-slot swizzle (0-conflict proven r3/r4) unchanged.
// EPI 1: fp32 row-major; EPI 3: routed QKV projection; EPI 4: fp16 row-major.
// ---------------------------------------------------------------------------
template<int EPI, int SWZ>
__global__ __launch_bounds__(512, 2) void gemm256_bt(
    const __hip_bfloat16* __restrict__ A,
    const __hip_bfloat16* __restrict__ Bt,
    void* __restrict__ Cv,
    int M, int N, int Kd,
    long zsA, long zsB, long zsC)
{
  __shared__ __hip_bfloat16 lds[3][2][256][32];   // 96 KiB

  int bx, by, bz;
  if (SWZ == 1) {        // scores: grid (16,16,4) -> lin in [0,1024)
    const int lin = blockIdx.x + (blockIdx.y << 4) + (blockIdx.z << 8);
    const int x7  = lin & 7;
    const int idx = (lin >> 3) & 31;
    bz = lin >> 8;
    by = ((x7 & 3) << 2) + (idx & 3);        // bm 0..15
    bx = ((x7 >> 2) << 3) + (idx >> 2);      // bn 0..15
  } else if (SWZ == 2) { // PV: grid (4,16,4) -> lin in [0,256)
    const int lin = blockIdx.x + (blockIdx.y << 2) + (blockIdx.z << 6);
    const int x7  = lin & 7;
    const int idx = (lin >> 3) & 31;
    const int zb  = (x7 << 1) + (idx >> 4);  // 0..15 = (z,bn)
    bz = zb >> 2;
    bx = zb & 3;                             // bn 0..3
    by = idx & 15;                           // bm 0..15
  } else {
    bx = blockIdx.x; by = blockIdx.y; bz = blockIdx.z;
  }

  A  += (long)bz * zsA;
  Bt += (long)bz * zsB;

  const int tid  = threadIdx.x;
  const int lane = tid & 63;
  const int wid  = tid >> 6;    // 0..7
  const int wm   = wid >> 2;    // 0..1
  const int wn   = wid & 3;     // 0..3
  const long bm  = (long)by * 256;
  const long bn  = (long)bx * 256;

  const int lrow  = lane >> 2;  // 0..15
  const int pslot = lane & 3;   // physical 16B slot this lane fills

  f32x4 acc[8][4];
#pragma unroll
  for (int i = 0; i < 8; ++i)
#pragma unroll
    for (int j = 0; j < 4; ++j)
      acc[i][j] = (f32x4){0.f, 0.f, 0.f, 0.f};

  const int NK = Kd >> 5;

  // Stage K-tile kt into buffer b: per wave 4 gload_lds (= 4 vmcnt units).
#define STAGE256(b, kt)                                                        \
  {                                                                            \
    _Pragma("unroll")                                                          \
    for (int half = 0; half < 2; ++half) {                                     \
      const int r  = wid * 32 + half * 16 + lrow;                              \
      const int ks = (pslot - ((r >> 1) & 3)) & 3;                             \
      const int kA = ((kt) << 5) + (ks << 3);                                  \
      gload_lds16(A  + (size_t)(bm + r) * Kd + kA,                             \
                  &lds[b][0][wid * 32 + half * 16][0]);                        \
      gload_lds16(Bt + (size_t)(bn + r) * Kd + kA,                             \
                  &lds[b][1][wid * 32 + half * 16][0]);                        \
    }                                                                          \
  }

  STAGE256(0, 0);
  if (NK > 1) STAGE256(1, 1);

  int buf = 0;   // buffer holding tile i
  int sb  = 2;   // buffer receiving tile i+2

  const int frow  = lane & 15;
  const int fslot = lane >> 4;  // logical k-slot

  for (int i = 0; i < NK; ++i) {
    if (i + 2 < NK) {
      STAGE256(sb, i + 2);
      WAITVM8;
    } else if (i + 2 == NK) {
      WAITVM4;
    } else {
      WAITVM0;
    }
    SCHEDB;
    SBAR;        // all waves' slices of tile i are in LDS
    SCHEDB;

    // ---- phase 1: B fragments + mi 0..3 ----
    s16x8 bfv[4];
#pragma unroll
    for (int ni = 0; ni < 4; ++ni) {
      const int r = wn * 64 + ni * 16 + frow;
      bfv[ni] = *(const s16x8*)&lds[buf][1][r][((fslot + (r >> 1)) & 3) << 3];
    }
    __builtin_amdgcn_s_setprio(1);
#pragma unroll
    for (int mi = 0; mi < 4; ++mi) {
      const int r = wm * 128 + mi * 16 + frow;
      const s16x8 af =
          *(const s16x8*)&lds[buf][0][r][((fslot + (r >> 1)) & 3) << 3];
#pragma unroll
      for (int ni = 0; ni < 4; ++ni)
        acc[mi][ni] = __builtin_amdgcn_mfma_f32_16x16x32_bf16(
            af, bfv[ni], acc[mi][ni], 0, 0, 0);
    }
    __builtin_amdgcn_s_setprio(0);

    SBAR;        // alignment only: staggers waves' LDS-read vs MFMA phases

    // ---- phase 2: mi 4..7 ----
    __builtin_amdgcn_s_setprio(1);
#pragma unroll
    for (int mi = 4; mi < 8; ++mi) {
      const int r = wm * 128 + mi * 16 + frow;
      const s16x8 af =
          *(const s16x8*)&lds[buf][0][r][((fslot + (r >> 1)) & 3) << 3];
#pragma unroll
      for (int ni = 0; ni < 4; ++ni)
        acc[mi][ni] = __builtin_amdgcn_mfma_f32_16x16x32_bf16(
            af, bfv[ni], acc[mi][ni], 0, 0, 0);
    }
    __builtin_amdgcn_s_setprio(0);

    WAITLGKM0;   // all this wave's ds_reads consumed
    SCHEDB;
    SBAR;        // nobody overwrites buf until every wave is done reading
    SCHEDB;

    buf = (buf == 2) ? 0 : buf + 1;
    sb  = (sb  == 2) ? 0 : sb  + 1;
  }

  // epilogue: C/D frag mapping col=lane&15, row=(lane>>4)*4+j  [m89]
  const int col   = lane & 15;
  const int rquad = (lane >> 4) << 2;
#pragma unroll
  for (int mi = 0; mi < 8; ++mi) {
#pragma unroll
    for (int ni = 0; ni < 4; ++ni) {
      const long m0 = bm + wm * 128 + mi * 16 + rquad;
      const long n  = bn + wn * 64 + ni * 16 + col;
#pragma unroll
      for (int j = 0; j < 4; ++j) {
        const float v = acc[mi][ni][j];
        if (EPI == 1) {
          float* C = (float*)Cv + (long)bz * zsC;
          C[(size_t)(m0 + j) * N + n] = v;
        } else if (EPI == 4) {
          short* C = (short*)Cv + (long)bz * zsC;
          C[(size_t)(m0 + j) * N + n] = f16_bits(v);
        } else {  // EPI == 3, merged projection (route uniform per block)
          const int route = (int)(bn >> 10);
          __hip_bfloat16* base = (__hip_bfloat16*)Cv + (long)route * 16777216L;
          const long nl = n & 1023;
          const long m  = m0 + j;
          if (route < 2) {
            base[(size_t)m * 1024 + nl] = __float2bfloat16(v);
          } else {
            const long b = m >> 12;
            const long s = m & 4095;
            base[(((b << 10) + nl) << 12) + s] = __float2bfloat16(v);
          }
        }
      }
    }
  }
}

// ---------------------------------------------------------------------------
__global__ __launch_bounds__(256) void cvt_f32_bf16(
    const float* __restrict__ x, __hip_bfloat16* __restrict__ o, long n)
{
  const long i = ((long)blockIdx.x * 256 + threadIdx.x) * 8;
  if (i >= n) return;
  f32x4 a = *(const f32x4*)(x + i);
  f32x4 b = *(const f32x4*)(x + i + 4);
  s16x8 r;
  r[0] = bf16_bits(a.x); r[1] = bf16_bits(a.y);
  r[2] = bf16_bits(a.z); r[3] = bf16_bits(a.w);
  r[4] = bf16_bits(b.x); r[5] = bf16_bits(b.y);
  r[6] = bf16_bits(b.z); r[7] = bf16_bits(b.w);
  *(s16x8*)((short*)o + i) = r;
}

// Wt[n][k] = W[k][n], fp32 -> bf16, D=1024
__global__ __launch_bounds__(256) void transpose_w_bf16(
    const float* __restrict__ W, __hip_bfloat16* __restrict__ Wt)
{
  __shared__ float t[32][33];
  const int tx = threadIdx.x & 31;
  const int ty = (threadIdx.x >> 5) * 4;
  const int bx = blockIdx.x * 32;  // n
  const int by = blockIdx.y * 32;  // k
#pragma unroll
  for (int j = 0; j < 4; ++j)
    t[ty + j][tx] = W[(size_t)(by + ty + j) * 1024 + bx + tx];
  __syncthreads();
#pragma unroll
  for (int j = 0; j < 4; ++j)
    Wt[(size_t)(bx + ty + j) * 1024 + by + tx] = __float2bfloat16(t[tx][ty + j]);
}

// In-place row softmax over fp16 scores -> bf16 probs, row width 4096.
__global__ __launch_bounds__(256) void softmax_inplace(
    short* __restrict__ scP, float scale)
{
  __shared__ float red[4];
  const int t = threadIdx.x;
  short* pr = scP + (long)blockIdx.x * 4096;

  s16x8 h0 = *(const s16x8*)(pr + t * 8);
  s16x8 h1 = *(const s16x8*)(pr + 2048 + t * 8);
  float v[16];
  float mx = -3.4e38f;
#pragma unroll
  for (int j = 0; j < 8; ++j) { v[j]     = f16_to_f32(h0[j]); }
#pragma unroll
  for (int j = 0; j < 8; ++j) { v[8 + j] = f16_to_f32(h1[j]); }
#pragma unroll
  for (int i = 0; i < 16; ++i) mx = fmaxf(mx, v[i]);
#pragma unroll
  for (int off = 32; off >= 1; off >>= 1) mx = fmaxf(mx, __shfl_xor(mx, off));
  if ((t & 63) == 0) red[t >> 6] = mx;
  __syncthreads();
  mx = fmaxf(fmaxf(red[0], red[1]), fmaxf(red[2], red[3]));
  __syncthreads();

  float sum = 0.f;
#pragma unroll
  for (int i = 0; i < 16; ++i) { v[i] = __expf((v[i] - mx) * scale); sum += v[i]; }
#pragma unroll
  for (int off = 32; off >= 1; off >>= 1) sum += __shfl_xor(sum, off);
  if ((t & 63) == 0) red[t >> 6] = sum;
  __syncthreads();
  sum = red[0] + red[1] + red[2] + red[3];
  const float inv = 1.f / sum;

  s16x8 o0, o1;
#pragma unroll
  for (int j = 0; j < 8; ++j) { o0[j] = bf16_bits(v[j] * inv); }
#pragma unroll
  for (int j = 0; j < 8; ++j) { o1[j] = bf16_bits(v[8 + j] * inv); }
  *(s16x8*)(pr + t * 8) = o0;
  *(s16x8*)(pr + 2048 + t * 8) = o1;
}

// ---------------------------------------------------------------------------
extern "C" void kernel_launch(void* const* d_in, const int* in_sizes, int n_in,
                              void* d_out, int out_size, void* d_ws, size_t ws_size,
                              hipStream_t stream) {
  (void)in_sizes; (void)n_in; (void)out_size; (void)ws_size;
  const float* x  = (const float*)d_in[0];
  const float* Wq = (const float*)d_in[1];
  const float* Wk = (const float*)d_in[2];
  const float* Wv = (const float*)d_in[3];
  float* out = (float*)d_out;

  char* ws = (char*)d_ws;
  // layout (bytes): qb 32M | kb 32M | vt 32M | wt 6M | scP 128M  = 235.2MB
  // xb (bf16 x, 32M) ALIASES scP head: dead after the projection GEMM.
  __hip_bfloat16* qb  = (__hip_bfloat16*)(ws);
  __hip_bfloat16* kb  = (__hip_bfloat16*)(ws + 33554432L);
  __hip_bfloat16* vt  = (__hip_bfloat16*)(ws + 67108864L);
  __hip_bfloat16* wt  = (__hip_bfloat16*)(ws + 100663296L);   // [3072][1024]
  short*          scP = (short*)         (ws + 106954752L);   // [4][4096][4096]
  __hip_bfloat16* xb  = (__hip_bfloat16*)(ws + 106954752L);   // alias

  cvt_f32_bf16<<<8192, 256, 0, stream>>>(x, xb, 16777216L);
  transpose_w_bf16<<<dim3(32, 32), 256, 0, stream>>>(Wq, wt);
  transpose_w_bf16<<<dim3(32, 32), 256, 0, stream>>>(Wk, wt + 1048576L);
  transpose_w_bf16<<<dim3(32, 32), 256, 0, stream>>>(Wv, wt + 2097152L);

  // merged QKV projection: [16384,1024] x [1024,3072]^T, routed epilogue
  gemm256_bt<3, 0><<<dim3(12, 64, 1), 512, 0, stream>>>(
      xb, wt, qb, 16384, 3072, 1024, 0L, 0L, 0L);

  // scores = Q K^T (fp16 out), z-batched, XCD-compact swizzle: 1024 blocks
  gemm256_bt<4, 1><<<dim3(16, 16, 4), 512, 0, stream>>>(
      qb, kb, scP, 4096, 4096, 1024,
      4194304L, 4194304L, 16777216L);

  // P = softmax(scale * scores) in place (fp16 -> bf16)
  softmax_inplace<<<16384, 256, 0, stream>>>(scP, 0.03125f);

  // O = P V via P[4096,4096] x Vt[1024,4096]^T, XCD swizzle: 256 blocks
  gemm256_bt<1, 2><<<dim3(4, 16, 4), 512, 0, stream>>>(
      (const __hip_bfloat16*)scP, vt, out, 4096, 1024, 4096,
      16777216L, 4194304L, 4194304L);
}